// Round 10
// baseline (126.038 us; speedup 1.0000x reference)
//
#include <hip/hip_runtime.h>
#include <hip/hip_bf16.h>
#include <math.h>

#define LL 8192
#define CC 256
#define SS 16
#define NJ (CC*SS)      // 4096 chains
#define GG 256          // chunks
#define TT 32           // rows per chunk
#define SEGS 16
#define PER (GG/SEGS)   // 16 chunks per carry segment

#define LOG2E 1.4426950408889634f
#define LN2   0.6931471805599453f

typedef __attribute__((ext_vector_type(8))) short short8;
typedef __attribute__((ext_vector_type(4))) float floatx4;

__device__ __forceinline__ float fexp2(float v){ return __builtin_amdgcn_exp2f(v); }
__device__ __forceinline__ float flog2v(float v){ return __builtin_amdgcn_logf(v); }

__device__ __forceinline__ float softplus(float z){
    float t = fexp2(-fabsf(z) * LOG2E);
    return fmaxf(z, 0.f) + LN2 * flog2v(1.f + t);
}

__device__ __forceinline__ void load16(float* d, const float* __restrict__ p){
    *(float4*)&d[0]  = *(const float4*)&p[0];
    *(float4*)&d[4]  = *(const float4*)&p[4];
    *(float4*)&d[8]  = *(const float4*)&p[8];
    *(float4*)&d[12] = *(const float4*)&p[12];
}

__device__ __forceinline__ unsigned short f2b(float f){
    __hip_bfloat16 h = __float2bfloat16(f);
    return *(unsigned short*)&h;
}
__device__ __forceinline__ float b2f(unsigned short u){
    __hip_bfloat16 h = *(__hip_bfloat16*)&u;
    return __bfloat162float(h);
}

// ============ k_mm: split-bf16 MFMA GEMM, in-kernel fp32->hi/lo casts ========
// grid (128, 9): bx = M-tile (row-fast => XCD-local x slabs), by = N-tile.
// Cols: [0,256)=dt, [256,272)=boa, [272,288)=cm. z = xh@Wh + xh@Wl + xl@Wh.
#define MBM 64
#define MBN 32
#define MBK 64
#define ASTR 72

__global__ __launch_bounds__(256,4) void k_mm(
    const float* __restrict__ x,
    const float* __restrict__ Wdt, const float* __restrict__ WB,
    const float* __restrict__ WC,
    const float* __restrict__ bdt, const float* __restrict__ bB,
    const float* __restrict__ bC, const float* __restrict__ logA,
    float* __restrict__ dt, float* __restrict__ boa, float* __restrict__ cm)
{
    __shared__ unsigned short Ah[MBM*ASTR];
    __shared__ unsigned short Al[MBM*ASTR];
    __shared__ unsigned short Bh[MBN*ASTR];
    __shared__ unsigned short Bl[MBN*ASTR];

    const int tid  = threadIdx.x;
    const int row0 = blockIdx.x * MBM;
    const int n0   = blockIdx.y * MBN;

    const int lane = tid & 63;
    const int wv   = tid >> 6;
    const int wm   = wv >> 1;
    const int wn   = wv & 1;
    const int m16  = lane & 15;
    const int q    = lane >> 4;

    const int bn  = tid & 31;
    const int bkb = (tid >> 5) * 8;
    const int bcol = n0 + bn;
    const float* __restrict__ wp;
    int wstride;
    if (bcol < 256)      { wp = Wdt + bcol;       wstride = CC; }
    else if (bcol < 272) { wp = WB  + (bcol-256); wstride = SS; }
    else                 { wp = WC  + (bcol-272); wstride = SS; }

    floatx4 acc[2];
    acc[0] = (floatx4){0.f,0.f,0.f,0.f};
    acc[1] = (floatx4){0.f,0.f,0.f,0.f};

    for (int k0 = 0; k0 < CC; k0 += MBK) {
        __syncthreads();
        #pragma unroll
        for (int h2 = 0; h2 < 2; h2++){
            int chunk = tid + h2*256;
            int r    = chunk >> 3;
            int koff = (chunk & 7) * 8;
            float4 f0 = *(const float4*)&x[(size_t)(row0+r)*CC + k0 + koff];
            float4 f1 = *(const float4*)&x[(size_t)(row0+r)*CC + k0 + koff + 4];
            float fv[8] = {f0.x,f0.y,f0.z,f0.w,f1.x,f1.y,f1.z,f1.w};
            unsigned short hs[8], ls[8];
            #pragma unroll
            for (int i=0;i<8;i++){
                hs[i] = f2b(fv[i]);
                ls[i] = f2b(fv[i] - b2f(hs[i]));
            }
            uint4 ph, pl;
            ph.x = (unsigned)hs[0] | ((unsigned)hs[1] << 16);
            ph.y = (unsigned)hs[2] | ((unsigned)hs[3] << 16);
            ph.z = (unsigned)hs[4] | ((unsigned)hs[5] << 16);
            ph.w = (unsigned)hs[6] | ((unsigned)hs[7] << 16);
            pl.x = (unsigned)ls[0] | ((unsigned)ls[1] << 16);
            pl.y = (unsigned)ls[2] | ((unsigned)ls[3] << 16);
            pl.z = (unsigned)ls[4] | ((unsigned)ls[5] << 16);
            pl.w = (unsigned)ls[6] | ((unsigned)ls[7] << 16);
            *(uint4*)&Ah[r*ASTR + koff] = ph;
            *(uint4*)&Al[r*ASTR + koff] = pl;
        }
        {
            unsigned short hs[8], ls[8];
            #pragma unroll
            for (int i=0;i<8;i++){
                float v = wp[(size_t)(k0 + bkb + i)*wstride];
                hs[i] = f2b(v);
                ls[i] = f2b(v - b2f(hs[i]));
            }
            uint4 ph, pl;
            ph.x = (unsigned)hs[0] | ((unsigned)hs[1] << 16);
            ph.y = (unsigned)hs[2] | ((unsigned)hs[3] << 16);
            ph.z = (unsigned)hs[4] | ((unsigned)hs[5] << 16);
            ph.w = (unsigned)hs[6] | ((unsigned)hs[7] << 16);
            pl.x = (unsigned)ls[0] | ((unsigned)ls[1] << 16);
            pl.y = (unsigned)ls[2] | ((unsigned)ls[3] << 16);
            pl.z = (unsigned)ls[4] | ((unsigned)ls[5] << 16);
            pl.w = (unsigned)ls[6] | ((unsigned)ls[7] << 16);
            *(uint4*)&Bh[bn*ASTR + bkb] = ph;
            *(uint4*)&Bl[bn*ASTR + bkb] = pl;
        }
        __syncthreads();

        #pragma unroll
        for (int ks = 0; ks < MBK; ks += 32) {
            short8 bh = *(const short8*)&Bh[(wn*16 + m16)*ASTR + ks + q*8];
            short8 bl = *(const short8*)&Bl[(wn*16 + m16)*ASTR + ks + q*8];
            #pragma unroll
            for (int mt = 0; mt < 2; mt++){
                short8 ah = *(const short8*)&Ah[(wm*32 + mt*16 + m16)*ASTR + ks + q*8];
                short8 al = *(const short8*)&Al[(wm*32 + mt*16 + m16)*ASTR + ks + q*8];
                acc[mt] = __builtin_amdgcn_mfma_f32_16x16x32_bf16(al, bh, acc[mt], 0, 0, 0);
                acc[mt] = __builtin_amdgcn_mfma_f32_16x16x32_bf16(ah, bl, acc[mt], 0, 0, 0);
                acc[mt] = __builtin_amdgcn_mfma_f32_16x16x32_bf16(ah, bh, acc[mt], 0, 0, 0);
            }
        }
    }

    const int col = n0 + wn*16 + m16;
    if (col < 256) {
        float bias = bdt[col];
        #pragma unroll
        for (int mt = 0; mt < 2; mt++){
            #pragma unroll
            for (int r = 0; r < 4; r++){
                int row = row0 + wm*32 + mt*16 + q*4 + r;
                dt[(size_t)row*CC + col] = softplus(0.01f + acc[mt][r] + bias);
            }
        }
    } else if (col < 272) {
        int s = col - 256;
        float A = -fexp2(logA[s] * LOG2E);
        float sc = LOG2E / A;
        float bias = bB[s];
        #pragma unroll
        for (int mt = 0; mt < 2; mt++){
            #pragma unroll
            for (int r = 0; r < 4; r++){
                int row = row0 + wm*32 + mt*16 + q*4 + r;
                boa[(size_t)row*SS + s] = (1.f + acc[mt][r] + bias) * sc;
            }
        }
    } else {
        int s = col - 272;
        float bias = bC[s];
        #pragma unroll
        for (int mt = 0; mt < 2; mt++){
            #pragma unroll
            for (int r = 0; r < 4; r++){
                int row = row0 + wm*32 + mt*16 + q*4 + r;
                cm[(size_t)row*SS + s] = acc[mt][r] + bias;
            }
        }
    }
}

// ============ k_scan1: thread=channel, TT=32 unrolled, boa in LDS ============
__global__ __launch_bounds__(256) void k_scan1(const float* __restrict__ dt,
    const float* __restrict__ x, const float* __restrict__ boa,
    const float* __restrict__ logA,
    float* __restrict__ Ap, float* __restrict__ Hl)
{
    const int c = threadIdx.x;
    const int g = blockIdx.x;
    const int row0 = g * TT;

    __shared__ float boS[TT*SS];      // 512 floats
    boS[c]       = boa[(size_t)row0*SS + c];
    boS[c + 256] = boa[(size_t)row0*SS + c + 256];

    float Al2[SS];
    #pragma unroll
    for (int s=0;s<SS;s++) Al2[s] = -fexp2(logA[s]*LOG2E) * LOG2E;  // A*log2e

    const float* __restrict__ dp = dt + (size_t)row0*CC + c;
    const float* __restrict__ xp = x  + (size_t)row0*CC + c;

    float Apr[SS], h[SS];
    #pragma unroll
    for (int s=0;s<SS;s++){ Apr[s]=1.f; h[s]=0.f; }

    __syncthreads();

    #pragma unroll
    for (int t=0;t<TT;t++){
        float d  = dp[t*CC];
        float xv = xp[t*CC];
        float bo[SS]; load16(bo, &boS[t*SS]);
        #pragma unroll
        for (int s=0;s<SS;s++){
            float a = fexp2(d * Al2[s]);
            float u = fexp2(fmaf(a, bo[s], -bo[s])) * xv;
            h[s] = fmaf(a, h[s], u);
            Apr[s] *= a;
        }
    }

    const size_t base = (size_t)g*NJ + c*SS;
    *(float4*)&Ap[base+0]  = make_float4(Apr[0],Apr[1],Apr[2],Apr[3]);
    *(float4*)&Ap[base+4]  = make_float4(Apr[4],Apr[5],Apr[6],Apr[7]);
    *(float4*)&Ap[base+8]  = make_float4(Apr[8],Apr[9],Apr[10],Apr[11]);
    *(float4*)&Ap[base+12] = make_float4(Apr[12],Apr[13],Apr[14],Apr[15]);
    *(float4*)&Hl[base+0]  = make_float4(h[0],h[1],h[2],h[3]);
    *(float4*)&Hl[base+4]  = make_float4(h[4],h[5],h[6],h[7]);
    *(float4*)&Hl[base+8]  = make_float4(h[8],h[9],h[10],h[11]);
    *(float4*)&Hl[base+12] = make_float4(h[12],h[13],h[14],h[15]);
}

// ============ k_carry: seg-parallel scan, PER=16 held in registers ===========
__global__ __launch_bounds__(256) void k_carry(const float* __restrict__ Ap,
    const float* __restrict__ Hl, float* __restrict__ Cr)
{
    const int tid = threadIdx.x;
    const int jl  = tid & 15;
    const int seg = tid >> 4;
    const int j   = blockIdx.x * 16 + jl;

    const size_t base = (size_t)(seg*PER)*NJ + j;

    float a[PER], u[PER];
    #pragma unroll
    for (int k=0;k<PER;k++){
        a[k] = Ap[base + (size_t)k*NJ];
        u[k] = Hl[base + (size_t)k*NJ];
    }
    float Aag = 1.f, Uag = 0.f;
    #pragma unroll
    for (int k=0;k<PER;k++){ Uag = fmaf(a[k], Uag, u[k]); Aag *= a[k]; }

    __shared__ float As[SEGS][17], Us[SEGS][17];
    As[seg][jl] = Aag; Us[seg][jl] = Uag;
    __syncthreads();
    float hin = 0.f;
    for (int t = 0; t < seg; ++t)
        hin = fmaf(As[t][jl], hin, Us[t][jl]);

    float h = hin;
    #pragma unroll
    for (int k=0;k<PER;k++){
        Cr[base + (size_t)k*NJ] = h;
        h = fmaf(a[k], h, u[k]);
    }
}

// ============ k_scan2: thread=channel; apply carry, contract to y ============
__global__ __launch_bounds__(256) void k_scan2(const float* __restrict__ dt,
    const float* __restrict__ x, const float* __restrict__ boa,
    const float* __restrict__ cmat, const float* __restrict__ logA,
    const float* __restrict__ Cr, float* __restrict__ y)
{
    const int c = threadIdx.x;
    const int g = blockIdx.x;
    const int row0 = g * TT;

    __shared__ float boS[TT*SS], cmS[TT*SS];   // 512 each
    boS[c]       = boa [(size_t)row0*SS + c];
    boS[c + 256] = boa [(size_t)row0*SS + c + 256];
    cmS[c]       = cmat[(size_t)row0*SS + c];
    cmS[c + 256] = cmat[(size_t)row0*SS + c + 256];

    float Al2[SS];
    #pragma unroll
    for (int s=0;s<SS;s++) Al2[s] = -fexp2(logA[s]*LOG2E) * LOG2E;

    const float* __restrict__ dp = dt + (size_t)row0*CC + c;
    const float* __restrict__ xp = x  + (size_t)row0*CC + c;
    float* __restrict__ yp = y + (size_t)row0*CC + c;

    float h[SS];
    load16(h, &Cr[(size_t)g*NJ + c*SS]);

    __syncthreads();

    #pragma unroll
    for (int t=0;t<TT;t++){
        float d  = dp[t*CC];
        float xv = xp[t*CC];
        float bo[SS]; load16(bo, &boS[t*SS]);
        float cmv[SS]; load16(cmv, &cmS[t*SS]);
        float yv = 0.f;
        #pragma unroll
        for (int s=0;s<SS;s++){
            float a = fexp2(d * Al2[s]);
            float u = fexp2(fmaf(a, bo[s], -bo[s])) * xv;
            h[s] = fmaf(a, h[s], u);
            yv = fmaf(cmv[s], h[s], yv);
        }
        yp[t*CC] = yv;
    }
}

extern "C" void kernel_launch(void* const* d_in, const int* in_sizes, int n_in,
                              void* d_out, int out_size, void* d_ws, size_t ws_size,
                              hipStream_t stream) {
    const float* x    = (const float*)d_in[0];
    const float* logA = (const float*)d_in[1];
    const float* W_dt = (const float*)d_in[2];
    const float* b_dt = (const float*)d_in[3];
    const float* W_B  = (const float*)d_in[4];
    const float* b_B  = (const float*)d_in[5];
    const float* W_C  = (const float*)d_in[6];
    const float* b_C  = (const float*)d_in[7];
    float* y  = (float*)d_out;
    float* ws = (float*)d_ws;

    float* dt   = ws;                            // L*C   = 2M floats
    float* boa  = dt   + (size_t)LL*CC;          // L*S
    float* cmv  = boa  + (size_t)LL*SS;          // L*S
    float* Ap   = cmv  + (size_t)LL*SS;          // GG*NJ = 1M
    float* Hl   = Ap   + (size_t)GG*NJ;          // GG*NJ
    float* Cr   = Hl   + (size_t)GG*NJ;          // GG*NJ  (~22 MB total)

    hipLaunchKernelGGL(k_mm,   dim3(128,9), dim3(256), 0, stream,
                       x, W_dt, W_B, W_C, b_dt, b_B, b_C, logA, dt, boa, cmv);
    hipLaunchKernelGGL(k_scan1, dim3(GG), dim3(256), 0, stream,
                       dt, x, boa, logA, Ap, Hl);
    hipLaunchKernelGGL(k_carry, dim3(NJ/16), dim3(256), 0, stream, Ap, Hl, Cr);
    hipLaunchKernelGGL(k_scan2, dim3(GG), dim3(256), 0, stream,
                       dt, x, boa, cmv, logA, Cr, y);
}

// Round 11
// 121.418 us; speedup vs baseline: 1.0380x; 1.0380x over previous
//
#include <hip/hip_runtime.h>
#include <hip/hip_bf16.h>
#include <math.h>

#define LL 8192
#define CC 256
#define SS 16
#define NJ (CC*SS)      // 4096 chains
#define GG 512          // chunks  (measured optimum: 1024->129, 512->122, 256->126)
#define TT 16           // rows per chunk
#define SEGS 16
#define PER (GG/SEGS)   // 32 chunks per carry segment

#define LOG2E 1.4426950408889634f
#define LN2   0.6931471805599453f

typedef __attribute__((ext_vector_type(8))) short short8;
typedef __attribute__((ext_vector_type(4))) float floatx4;

__device__ __forceinline__ float fexp2(float v){ return __builtin_amdgcn_exp2f(v); }
__device__ __forceinline__ float flog2v(float v){ return __builtin_amdgcn_logf(v); }

__device__ __forceinline__ float softplus(float z){
    float t = fexp2(-fabsf(z) * LOG2E);
    return fmaxf(z, 0.f) + LN2 * flog2v(1.f + t);
}

__device__ __forceinline__ void load16(float* d, const float* __restrict__ p){
    *(float4*)&d[0]  = *(const float4*)&p[0];
    *(float4*)&d[4]  = *(const float4*)&p[4];
    *(float4*)&d[8]  = *(const float4*)&p[8];
    *(float4*)&d[12] = *(const float4*)&p[12];
}

__device__ __forceinline__ unsigned short f2b(float f){
    __hip_bfloat16 h = __float2bfloat16(f);
    return *(unsigned short*)&h;
}
__device__ __forceinline__ float b2f(unsigned short u){
    __hip_bfloat16 h = *(__hip_bfloat16*)&u;
    return __bfloat162float(h);
}

// ============ k_mm: split-bf16 MFMA GEMM, in-kernel fp32->hi/lo casts ========
// grid (128, 9): bx = M-tile (row-fast => XCD-local x slabs), by = N-tile.
// Cols: [0,256)=dt, [256,272)=boa, [272,288)=cm. z = xh@Wh + xh@Wl + xl@Wh.
#define MBM 64
#define MBN 32
#define MBK 64
#define ASTR 72

__global__ __launch_bounds__(256,4) void k_mm(
    const float* __restrict__ x,
    const float* __restrict__ Wdt, const float* __restrict__ WB,
    const float* __restrict__ WC,
    const float* __restrict__ bdt, const float* __restrict__ bB,
    const float* __restrict__ bC, const float* __restrict__ logA,
    float* __restrict__ dt, float* __restrict__ boa, float* __restrict__ cm)
{
    __shared__ unsigned short Ah[MBM*ASTR];
    __shared__ unsigned short Al[MBM*ASTR];
    __shared__ unsigned short Bh[MBN*ASTR];
    __shared__ unsigned short Bl[MBN*ASTR];

    const int tid  = threadIdx.x;
    const int row0 = blockIdx.x * MBM;
    const int n0   = blockIdx.y * MBN;

    const int lane = tid & 63;
    const int wv   = tid >> 6;
    const int wm   = wv >> 1;
    const int wn   = wv & 1;
    const int m16  = lane & 15;
    const int q    = lane >> 4;

    const int bn  = tid & 31;
    const int bkb = (tid >> 5) * 8;
    const int bcol = n0 + bn;
    const float* __restrict__ wp;
    int wstride;
    if (bcol < 256)      { wp = Wdt + bcol;       wstride = CC; }
    else if (bcol < 272) { wp = WB  + (bcol-256); wstride = SS; }
    else                 { wp = WC  + (bcol-272); wstride = SS; }

    floatx4 acc[2];
    acc[0] = (floatx4){0.f,0.f,0.f,0.f};
    acc[1] = (floatx4){0.f,0.f,0.f,0.f};

    for (int k0 = 0; k0 < CC; k0 += MBK) {
        __syncthreads();
        #pragma unroll
        for (int h2 = 0; h2 < 2; h2++){
            int chunk = tid + h2*256;
            int r    = chunk >> 3;
            int koff = (chunk & 7) * 8;
            float4 f0 = *(const float4*)&x[(size_t)(row0+r)*CC + k0 + koff];
            float4 f1 = *(const float4*)&x[(size_t)(row0+r)*CC + k0 + koff + 4];
            float fv[8] = {f0.x,f0.y,f0.z,f0.w,f1.x,f1.y,f1.z,f1.w};
            unsigned short hs[8], ls[8];
            #pragma unroll
            for (int i=0;i<8;i++){
                hs[i] = f2b(fv[i]);
                ls[i] = f2b(fv[i] - b2f(hs[i]));
            }
            uint4 ph, pl;
            ph.x = (unsigned)hs[0] | ((unsigned)hs[1] << 16);
            ph.y = (unsigned)hs[2] | ((unsigned)hs[3] << 16);
            ph.z = (unsigned)hs[4] | ((unsigned)hs[5] << 16);
            ph.w = (unsigned)hs[6] | ((unsigned)hs[7] << 16);
            pl.x = (unsigned)ls[0] | ((unsigned)ls[1] << 16);
            pl.y = (unsigned)ls[2] | ((unsigned)ls[3] << 16);
            pl.z = (unsigned)ls[4] | ((unsigned)ls[5] << 16);
            pl.w = (unsigned)ls[6] | ((unsigned)ls[7] << 16);
            *(uint4*)&Ah[r*ASTR + koff] = ph;
            *(uint4*)&Al[r*ASTR + koff] = pl;
        }
        {
            unsigned short hs[8], ls[8];
            #pragma unroll
            for (int i=0;i<8;i++){
                float v = wp[(size_t)(k0 + bkb + i)*wstride];
                hs[i] = f2b(v);
                ls[i] = f2b(v - b2f(hs[i]));
            }
            uint4 ph, pl;
            ph.x = (unsigned)hs[0] | ((unsigned)hs[1] << 16);
            ph.y = (unsigned)hs[2] | ((unsigned)hs[3] << 16);
            ph.z = (unsigned)hs[4] | ((unsigned)hs[5] << 16);
            ph.w = (unsigned)hs[6] | ((unsigned)hs[7] << 16);
            pl.x = (unsigned)ls[0] | ((unsigned)ls[1] << 16);
            pl.y = (unsigned)ls[2] | ((unsigned)ls[3] << 16);
            pl.z = (unsigned)ls[4] | ((unsigned)ls[5] << 16);
            pl.w = (unsigned)ls[6] | ((unsigned)ls[7] << 16);
            *(uint4*)&Bh[bn*ASTR + bkb] = ph;
            *(uint4*)&Bl[bn*ASTR + bkb] = pl;
        }
        __syncthreads();

        #pragma unroll
        for (int ks = 0; ks < MBK; ks += 32) {
            short8 bh = *(const short8*)&Bh[(wn*16 + m16)*ASTR + ks + q*8];
            short8 bl = *(const short8*)&Bl[(wn*16 + m16)*ASTR + ks + q*8];
            #pragma unroll
            for (int mt = 0; mt < 2; mt++){
                short8 ah = *(const short8*)&Ah[(wm*32 + mt*16 + m16)*ASTR + ks + q*8];
                short8 al = *(const short8*)&Al[(wm*32 + mt*16 + m16)*ASTR + ks + q*8];
                acc[mt] = __builtin_amdgcn_mfma_f32_16x16x32_bf16(al, bh, acc[mt], 0, 0, 0);
                acc[mt] = __builtin_amdgcn_mfma_f32_16x16x32_bf16(ah, bl, acc[mt], 0, 0, 0);
                acc[mt] = __builtin_amdgcn_mfma_f32_16x16x32_bf16(ah, bh, acc[mt], 0, 0, 0);
            }
        }
    }

    const int col = n0 + wn*16 + m16;
    if (col < 256) {
        float bias = bdt[col];
        #pragma unroll
        for (int mt = 0; mt < 2; mt++){
            #pragma unroll
            for (int r = 0; r < 4; r++){
                int row = row0 + wm*32 + mt*16 + q*4 + r;
                dt[(size_t)row*CC + col] = softplus(0.01f + acc[mt][r] + bias);
            }
        }
    } else if (col < 272) {
        int s = col - 256;
        float A = -fexp2(logA[s] * LOG2E);
        float sc = LOG2E / A;
        float bias = bB[s];
        #pragma unroll
        for (int mt = 0; mt < 2; mt++){
            #pragma unroll
            for (int r = 0; r < 4; r++){
                int row = row0 + wm*32 + mt*16 + q*4 + r;
                boa[(size_t)row*SS + s] = (1.f + acc[mt][r] + bias) * sc;
            }
        }
    } else {
        int s = col - 272;
        float bias = bC[s];
        #pragma unroll
        for (int mt = 0; mt < 2; mt++){
            #pragma unroll
            for (int r = 0; r < 4; r++){
                int row = row0 + wm*32 + mt*16 + q*4 + r;
                cm[(size_t)row*SS + s] = acc[mt][r] + bias;
            }
        }
    }
}

// ============ k_scan1: thread=channel, TT=16 unrolled, boa in LDS ============
__global__ __launch_bounds__(256) void k_scan1(const float* __restrict__ dt,
    const float* __restrict__ x, const float* __restrict__ boa,
    const float* __restrict__ logA,
    float* __restrict__ Ap, float* __restrict__ Hl)
{
    const int c = threadIdx.x;
    const int g = blockIdx.x;
    const int row0 = g * TT;

    __shared__ float boS[TT*SS];      // 256 floats
    boS[c] = boa[(size_t)row0*SS + c];

    float Al2[SS];
    #pragma unroll
    for (int s=0;s<SS;s++) Al2[s] = -fexp2(logA[s]*LOG2E) * LOG2E;  // A*log2e

    const float* __restrict__ dp = dt + (size_t)row0*CC + c;
    const float* __restrict__ xp = x  + (size_t)row0*CC + c;

    float Apr[SS], h[SS];
    #pragma unroll
    for (int s=0;s<SS;s++){ Apr[s]=1.f; h[s]=0.f; }

    __syncthreads();

    #pragma unroll
    for (int t=0;t<TT;t++){
        float d  = dp[t*CC];
        float xv = xp[t*CC];
        float bo[SS]; load16(bo, &boS[t*SS]);
        #pragma unroll
        for (int s=0;s<SS;s++){
            float a = fexp2(d * Al2[s]);
            float u = fexp2(fmaf(a, bo[s], -bo[s])) * xv;
            h[s] = fmaf(a, h[s], u);
            Apr[s] *= a;
        }
    }

    const size_t base = (size_t)g*NJ + c*SS;
    *(float4*)&Ap[base+0]  = make_float4(Apr[0],Apr[1],Apr[2],Apr[3]);
    *(float4*)&Ap[base+4]  = make_float4(Apr[4],Apr[5],Apr[6],Apr[7]);
    *(float4*)&Ap[base+8]  = make_float4(Apr[8],Apr[9],Apr[10],Apr[11]);
    *(float4*)&Ap[base+12] = make_float4(Apr[12],Apr[13],Apr[14],Apr[15]);
    *(float4*)&Hl[base+0]  = make_float4(h[0],h[1],h[2],h[3]);
    *(float4*)&Hl[base+4]  = make_float4(h[4],h[5],h[6],h[7]);
    *(float4*)&Hl[base+8]  = make_float4(h[8],h[9],h[10],h[11]);
    *(float4*)&Hl[base+12] = make_float4(h[12],h[13],h[14],h[15]);
}

// ============ k_carry: seg-parallel scan, PER=32 held in registers ===========
__global__ __launch_bounds__(256) void k_carry(const float* __restrict__ Ap,
    const float* __restrict__ Hl, float* __restrict__ Cr)
{
    const int tid = threadIdx.x;
    const int jl  = tid & 15;
    const int seg = tid >> 4;
    const int j   = blockIdx.x * 16 + jl;

    const size_t base = (size_t)(seg*PER)*NJ + j;

    float a[PER], u[PER];
    #pragma unroll
    for (int k=0;k<PER;k++){
        a[k] = Ap[base + (size_t)k*NJ];
        u[k] = Hl[base + (size_t)k*NJ];
    }
    float Aag = 1.f, Uag = 0.f;
    #pragma unroll
    for (int k=0;k<PER;k++){ Uag = fmaf(a[k], Uag, u[k]); Aag *= a[k]; }

    __shared__ float As[SEGS][17], Us[SEGS][17];
    As[seg][jl] = Aag; Us[seg][jl] = Uag;
    __syncthreads();
    float hin = 0.f;
    for (int t = 0; t < seg; ++t)
        hin = fmaf(As[t][jl], hin, Us[t][jl]);

    float h = hin;
    #pragma unroll
    for (int k=0;k<PER;k++){
        Cr[base + (size_t)k*NJ] = h;
        h = fmaf(a[k], h, u[k]);
    }
}

// ============ k_scan2: thread=channel; apply carry, contract to y ============
__global__ __launch_bounds__(256) void k_scan2(const float* __restrict__ dt,
    const float* __restrict__ x, const float* __restrict__ boa,
    const float* __restrict__ cmat, const float* __restrict__ logA,
    const float* __restrict__ Cr, float* __restrict__ y)
{
    const int c = threadIdx.x;
    const int g = blockIdx.x;
    const int row0 = g * TT;

    __shared__ float boS[TT*SS], cmS[TT*SS];   // 256 each
    boS[c] = boa [(size_t)row0*SS + c];
    cmS[c] = cmat[(size_t)row0*SS + c];

    float Al2[SS];
    #pragma unroll
    for (int s=0;s<SS;s++) Al2[s] = -fexp2(logA[s]*LOG2E) * LOG2E;

    const float* __restrict__ dp = dt + (size_t)row0*CC + c;
    const float* __restrict__ xp = x  + (size_t)row0*CC + c;
    float* __restrict__ yp = y + (size_t)row0*CC + c;

    float h[SS];
    load16(h, &Cr[(size_t)g*NJ + c*SS]);

    __syncthreads();

    #pragma unroll
    for (int t=0;t<TT;t++){
        float d  = dp[t*CC];
        float xv = xp[t*CC];
        float bo[SS]; load16(bo, &boS[t*SS]);
        float cmv[SS]; load16(cmv, &cmS[t*SS]);
        float yv = 0.f;
        #pragma unroll
        for (int s=0;s<SS;s++){
            float a = fexp2(d * Al2[s]);
            float u = fexp2(fmaf(a, bo[s], -bo[s])) * xv;
            h[s] = fmaf(a, h[s], u);
            yv = fmaf(cmv[s], h[s], yv);
        }
        yp[t*CC] = yv;
    }
}

extern "C" void kernel_launch(void* const* d_in, const int* in_sizes, int n_in,
                              void* d_out, int out_size, void* d_ws, size_t ws_size,
                              hipStream_t stream) {
    const float* x    = (const float*)d_in[0];
    const float* logA = (const float*)d_in[1];
    const float* W_dt = (const float*)d_in[2];
    const float* b_dt = (const float*)d_in[3];
    const float* W_B  = (const float*)d_in[4];
    const float* b_B  = (const float*)d_in[5];
    const float* W_C  = (const float*)d_in[6];
    const float* b_C  = (const float*)d_in[7];
    float* y  = (float*)d_out;
    float* ws = (float*)d_ws;

    float* dt   = ws;                            // L*C   = 2M floats
    float* boa  = dt   + (size_t)LL*CC;          // L*S
    float* cmv  = boa  + (size_t)LL*SS;          // L*S
    float* Ap   = cmv  + (size_t)LL*SS;          // GG*NJ = 2M
    float* Hl   = Ap   + (size_t)GG*NJ;          // GG*NJ
    float* Cr   = Hl   + (size_t)GG*NJ;          // GG*NJ  (~33 MB total)

    hipLaunchKernelGGL(k_mm,   dim3(128,9), dim3(256), 0, stream,
                       x, W_dt, W_B, W_C, b_dt, b_B, b_C, logA, dt, boa, cmv);
    hipLaunchKernelGGL(k_scan1, dim3(GG), dim3(256), 0, stream,
                       dt, x, boa, logA, Ap, Hl);
    hipLaunchKernelGGL(k_carry, dim3(NJ/16), dim3(256), 0, stream, Ap, Hl, Cr);
    hipLaunchKernelGGL(k_scan2, dim3(GG), dim3(256), 0, stream,
                       dt, x, boa, cmv, logA, Cr, y);
}